// Round 12
// baseline (20.126 us; speedup 1.0000x reference)
//
#include <hip/hip_runtime.h>
#include <math.h>

// probs/targets: (32,1,512,512) fp32
// ROUND 12: VALU-pipe wave reduction (DPP row_ror + permlane swaps) — zero
// DS, zero LDS, zero syncthreads in k_partial. Geometry = the r5 probe's
// (2048 blocks, 16 elem/thread, 32 waves/CU, 13.7 TB/s proven) now that the
// reduction tail no longer scales with occupancy.
#define NS 32
#define NELEM 262144
#define TPB 256

__device__ __forceinline__ unsigned f2u(float x) { return __builtin_bit_cast(unsigned, x); }
__device__ __forceinline__ float u2f(unsigned x) { return __builtin_bit_cast(float, x); }

// branch-free (mx, pk=(cnt<<16)|gt) semigroup: replace on greater, add on equal
__device__ __forceinline__ void comb(float& mx, int& pk, float m2, int pk2) {
    const bool g = m2 > mx;
    const bool e = m2 == mx;
    pk = g ? pk2 : (pk + (e ? pk2 : 0));
    mx = fmaxf(mx, m2);
}

template<int CTRL>
__device__ __forceinline__ float dppf(float v) {
    return u2f((unsigned)__builtin_amdgcn_update_dpp((int)f2u(v), (int)f2u(v),
                                                     CTRL, 0xF, 0xF, false));
}
template<int CTRL>
__device__ __forceinline__ int dppi(int v) {
    return __builtin_amdgcn_update_dpp(v, v, CTRL, 0xF, 0xF, false);
}

// row_ror:N reduction level (within 16-lane rows) — pure VALU
template<int N>
__device__ __forceinline__ void level_ror(float& s1, float& s2, float& dt,
                                          int& cgt, float& mx, int& pk) {
    s1 += dppf<0x120 + N>(s1);
    s2 += dppf<0x120 + N>(s2);
    dt += dppf<0x120 + N>(dt);
    cgt += dppi<0x120 + N>(cgt);
    const float m2 = dppf<0x120 + N>(mx);
    const int   p2 = dppi<0x120 + N>(pk);
    comb(mx, pk, m2, p2);
}

#if __has_builtin(__builtin_amdgcn_permlane16_swap) && __has_builtin(__builtin_amdgcn_permlane32_swap)
// swap(a,a) returns both row/half variants -> combining the pair == xor level.
template<bool WIDE>
__device__ __forceinline__ void level_swap(float& s1, float& s2, float& dt,
                                           int& cgt, float& mx, int& pk) {
#define SWAP_(x) (WIDE ? __builtin_amdgcn_permlane32_swap((x), (x), false, false) \
                       : __builtin_amdgcn_permlane16_swap((x), (x), false, false))
    { auto r = SWAP_(f2u(s1)); s1 = u2f(r[0]) + u2f(r[1]); }
    { auto r = SWAP_(f2u(s2)); s2 = u2f(r[0]) + u2f(r[1]); }
    { auto r = SWAP_(f2u(dt)); dt = u2f(r[0]) + u2f(r[1]); }
    { auto r = SWAP_((unsigned)cgt); cgt = (int)(r[0] + r[1]); }
    { auto rm = SWAP_(f2u(mx));
      auto rp = SWAP_((unsigned)pk);
      float mA = u2f(rm[0]); int pA = (int)rp[0];
      comb(mA, pA, u2f(rm[1]), (int)rp[1]);
      mx = mA; pk = pA; }
#undef SWAP_
}
#else
template<bool WIDE>
__device__ __forceinline__ void level_swap(float& s1, float& s2, float& dt,
                                           int& cgt, float& mx, int& pk) {
    const int off = WIDE ? 32 : 16;
    s1 += __shfl_xor(s1, off);
    s2 += __shfl_xor(s2, off);
    dt += __shfl_xor(dt, off);
    cgt += __shfl_xor(cgt, off);
    const float m2 = __shfl_xor(mx, off);
    const int   p2 = __shfl_xor(pk, off);
    comb(mx, pk, m2, p2);
}
#endif

// PASSES x 16 elem/thread; one partial set per WAVE (no LDS, no barrier).
// ws float layout: s1[nsets] s2[nsets] dot[nsets] mx[nsets] | cgt[nsets] pk[nsets] (ints)
template<int PASSES, int MINW>
__global__ __launch_bounds__(TPB, MINW) void k_partial(const float* __restrict__ probs,
                                                       const float* __restrict__ tgts,
                                                       float* __restrict__ wsf,
                                                       int* __restrict__ wsi,
                                                       int nsets) {
    constexpr int BPS = NELEM / (PASSES * TPB * 16);   // blocks per sample
    const int b = blockIdx.x;
    const int s = b / BPS;
    const int c = b % BPS;
    const size_t base = (size_t)s * NELEM + (size_t)c * (PASSES * TPB * 16);
    const float4* __restrict__ p4 = (const float4*)(probs + base);
    const float4* __restrict__ t4 = (const float4*)(tgts + base);
    const int t = threadIdx.x;

    float4 a1 = {0.f,0.f,0.f,0.f}, a2 = {0.f,0.f,0.f,0.f}, ad = {0.f,0.f,0.f,0.f};
    int cgt = 0, pk = 0;
    float mx = -INFINITY;

#pragma unroll
    for (int g = 0; g < PASSES; ++g) {
        float4 pv[4], tv[4];
#pragma unroll
        for (int k = 0; k < 4; ++k) {
            pv[k] = p4[g * 1024 + k * 256 + t];
            tv[k] = t4[g * 1024 + k * 256 + t];
        }
        // component-parallel sums
#pragma unroll
        for (int k = 0; k < 4; ++k) {
            a1.x += pv[k].x; a1.y += pv[k].y; a1.z += pv[k].z; a1.w += pv[k].w;
            a2.x += tv[k].x; a2.y += tv[k].y; a2.z += tv[k].z; a2.w += tv[k].w;
            ad.x = fmaf(pv[k].x, tv[k].x, ad.x);
            ad.y = fmaf(pv[k].y, tv[k].y, ad.y);
            ad.z = fmaf(pv[k].z, tv[k].z, ad.z);
            ad.w = fmaf(pv[k].w, tv[k].w, ad.w);
        }
        // pass max via pairwise tree (depth 4)
        const float mX = fmaxf(fmaxf(tv[0].x, tv[1].x), fmaxf(tv[2].x, tv[3].x));
        const float mY = fmaxf(fmaxf(tv[0].y, tv[1].y), fmaxf(tv[2].y, tv[3].y));
        const float mZ = fmaxf(fmaxf(tv[0].z, tv[1].z), fmaxf(tv[2].z, tv[3].z));
        const float mW = fmaxf(fmaxf(tv[0].w, tv[1].w), fmaxf(tv[2].w, tv[3].w));
        const float mg = fmaxf(fmaxf(mX, mY), fmaxf(mZ, mW));
        // branch-free recount vs pass max
        int cp = 0, cg = 0, gg = 0;
#pragma unroll
        for (int k = 0; k < 4; ++k) {
            const float pc[4] = {pv[k].x, pv[k].y, pv[k].z, pv[k].w};
            const float tc[4] = {tv[k].x, tv[k].y, tv[k].z, tv[k].w};
#pragma unroll
            for (int j = 0; j < 4; ++j) {
                const int b1 = pc[j] > 0.5f;
                const int eq = tc[j] == mg;
                cp += b1;
                cg += eq;
                gg += eq & b1;
            }
        }
        cgt += cp;
        comb(mx, pk, mg, (cg << 16) | gg);   // fields <= 4096 at wave scope
    }

    float s1 = (a1.x + a1.y) + (a1.z + a1.w);
    float s2 = (a2.x + a2.y) + (a2.z + a2.w);
    float dt = (ad.x + ad.y) + (ad.z + ad.w);

    // full 64-lane reduce on the VALU pipe
    level_ror<8>(s1, s2, dt, cgt, mx, pk);
    level_ror<4>(s1, s2, dt, cgt, mx, pk);
    level_ror<2>(s1, s2, dt, cgt, mx, pk);
    level_ror<1>(s1, s2, dt, cgt, mx, pk);
    level_swap<false>(s1, s2, dt, cgt, mx, pk);   // lane^16
    level_swap<true >(s1, s2, dt, cgt, mx, pk);   // lane^32

    if ((t & 63) == 0) {
        const int g = b * (TPB / 64) + (t >> 6);  // one set per wave
        wsf[0 * nsets + g] = s1;
        wsf[1 * nsets + g] = s2;
        wsf[2 * nsets + g] = dt;
        wsf[3 * nsets + g] = mx;
        wsi[4 * nsets + g] = cgt;
        wsi[5 * nsets + g] = pk;
    }
}

__device__ __forceinline__ void combine_max(float& mx, int& cnt, int& gt,
                                            float mx2, int cnt2, int gt2) {
    if (mx2 > mx) { mx = mx2; cnt = cnt2; gt = gt2; }
    else if (mx2 == mx) { cnt += cnt2; gt += gt2; }
}

// one block per sample; SPS sets/sample, one per thread; unpack pk before
// reducing (sample-level counts exceed 16 bits)
template<int SPS>
__global__ __launch_bounds__(SPS) void k_sample(const float* __restrict__ wsf,
                                                const int* __restrict__ wsi,
                                                float* __restrict__ scores,
                                                int nsets) {
    const int s = blockIdx.x;
    const int t = threadIdx.x;
    const int idx = s * SPS + t;

    float s1 = wsf[0 * nsets + idx];
    float s2 = wsf[1 * nsets + idx];
    float dt = wsf[2 * nsets + idx];
    float mx = wsf[3 * nsets + idx];
    int  cgt = wsi[4 * nsets + idx];
    const int pk = wsi[5 * nsets + idx];
    int cnt = pk >> 16;
    int gt  = pk & 0xFFFF;

#pragma unroll
    for (int off = 32; off; off >>= 1) {
        s1  += __shfl_xor(s1, off);
        s2  += __shfl_xor(s2, off);
        dt  += __shfl_xor(dt, off);
        cgt += __shfl_xor(cgt, off);
        float m2 = __shfl_xor(mx, off);
        int   c2 = __shfl_xor(cnt, off);
        int   g2 = __shfl_xor(gt, off);
        combine_max(mx, cnt, gt, m2, c2, g2);
    }

    if constexpr (SPS > 64) {
        __shared__ float ls1[SPS / 64], ls2[SPS / 64], ldt[SPS / 64], lmx[SPS / 64];
        __shared__ int   lcg[SPS / 64], lcn[SPS / 64], lgt[SPS / 64];
        const int w = t >> 6;
        if ((t & 63) == 0) {
            ls1[w] = s1; ls2[w] = s2; ldt[w] = dt; lmx[w] = mx;
            lcg[w] = cgt; lcn[w] = cnt; lgt[w] = gt;
        }
        __syncthreads();
        if (t == 0) {
#pragma unroll
            for (int w2 = 1; w2 < SPS / 64; ++w2) {
                s1 += ls1[w2]; s2 += ls2[w2]; dt += ldt[w2]; cgt += lcg[w2];
                combine_max(mx, cnt, gt, lmx[w2], lcn[w2], lgt[w2]);
            }
        }
    }

    if (t == 0) {
        const int cle = NELEM - cgt;   // count(p <= 0.5)
        const long long corr = (long long)cle - (long long)cnt + 2LL * (long long)gt;
        float score = 2.0f * (dt + 1.0f) / (s1 + s2 + 1.0f);
        if (corr == 1) score = 1.0f;   // acc == 1.0 (probs.shape[1] == 1)
        scores[s] = 1.0f - score;
    }
}

__global__ __launch_bounds__(64) void k_mean(const float* __restrict__ scores,
                                             float* __restrict__ out) {
    const int t = threadIdx.x;
    float v = (t < NS) ? scores[t] : 0.0f;
#pragma unroll
    for (int off = 32; off; off >>= 1) v += __shfl_xor(v, off);
    if (t == 0) out[0] = v * (1.0f / (float)NS);
}

extern "C" void kernel_launch(void* const* d_in, const int* in_sizes, int n_in,
                              void* d_out, int out_size, void* d_ws, size_t ws_size,
                              hipStream_t stream) {
    const float* probs = (const float*)d_in[0];
    const float* tgts  = (const float*)d_in[1];
    float* wsf = (float*)d_ws;
    int*   wsi = (int*)d_ws;
    float* out = (float*)d_out;

    // primary: 2048 blocks (probe-proven streaming), 8192 sets = 196 KB ws
    const size_t need_big = (size_t)(6 * 8192 + NS) * sizeof(float);
    if (ws_size >= need_big) {
        const int nsets = 8192;
        k_partial<1, 8><<<2048, TPB, 0, stream>>>(probs, tgts, wsf, wsi, nsets);
        k_sample<256><<<NS, 256, 0, stream>>>(wsf, wsi, wsf + 6 * nsets, nsets);
        k_mean<<<1, 64, 0, stream>>>(wsf + 6 * nsets, out);
    } else {
        // fallback: 512 blocks, 2048 sets = 49 KB ws (proven size range)
        const int nsets = 2048;
        k_partial<4, 4><<<512, TPB, 0, stream>>>(probs, tgts, wsf, wsi, nsets);
        k_sample<64><<<NS, 64, 0, stream>>>(wsf, wsi, wsf + 6 * nsets, nsets);
        k_mean<<<1, 64, 0, stream>>>(wsf + 6 * nsets, out);
    }
}